// Round 1
// baseline (730.398 us; speedup 1.0000x reference)
//
#include <hip/hip_runtime.h>

#define D 128

// ---------------------------------------------------------------- utilities

__global__ void zero_counts_k(int* __restrict__ counts, int n) {
    int i = blockIdx.x * blockDim.x + threadIdx.x;
    if (i < n) counts[i] = 0;
}

__global__ void count_deg_k(const int* __restrict__ dst, int* __restrict__ counts, int E) {
    int e = blockIdx.x * blockDim.x + threadIdx.x;
    if (e < E) atomicAdd(&counts[dst[e]], 1);
}

// Block-level exclusive scan: 1024 elements per block (256 thr x 4).
__global__ void scan_block_k(const int* __restrict__ counts, int* __restrict__ offsets,
                             int* __restrict__ blocksums, int n) {
    __shared__ int sh[256];
    int t = threadIdx.x;
    int base = blockIdx.x * 1024 + t * 4;
    int v0 = (base + 0 < n) ? counts[base + 0] : 0;
    int v1 = (base + 1 < n) ? counts[base + 1] : 0;
    int v2 = (base + 2 < n) ? counts[base + 2] : 0;
    int v3 = (base + 3 < n) ? counts[base + 3] : 0;
    int tsum = v0 + v1 + v2 + v3;
    sh[t] = tsum;
    __syncthreads();
    // Hillis-Steele inclusive scan over 256 thread sums
    for (int off = 1; off < 256; off <<= 1) {
        int x = 0;
        if (t >= off) x = sh[t - off];
        __syncthreads();
        if (t >= off) sh[t] += x;
        __syncthreads();
    }
    int excl = sh[t] - tsum;   // exclusive prefix of this thread's chunk
    if (base + 0 < n) offsets[base + 0] = excl;
    if (base + 1 < n) offsets[base + 1] = excl + v0;
    if (base + 2 < n) offsets[base + 2] = excl + v0 + v1;
    if (base + 3 < n) offsets[base + 3] = excl + v0 + v1 + v2;
    if (t == 255) blocksums[blockIdx.x] = sh[255];
}

// Exclusive scan of block sums (nb <= 256), single block.
__global__ void scan_top_k(int* __restrict__ blocksums, int nb) {
    __shared__ int sh[256];
    int t = threadIdx.x;
    int v = (t < nb) ? blocksums[t] : 0;
    sh[t] = v;
    __syncthreads();
    for (int off = 1; off < 256; off <<= 1) {
        int x = 0;
        if (t >= off) x = sh[t - off];
        __syncthreads();
        if (t >= off) sh[t] += x;
        __syncthreads();
    }
    if (t < nb) blocksums[t] = sh[t] - v;   // exclusive
}

__global__ void scan_add_k(int* __restrict__ offsets, int* __restrict__ cursor,
                           const int* __restrict__ blocksums, int n) {
    int i = blockIdx.x * blockDim.x + threadIdx.x;
    if (i < n) {
        int o = offsets[i] + blocksums[i >> 10];
        offsets[i] = o;
        cursor[i]  = o;
    }
}

__global__ void scatter_k(const int* __restrict__ src, const int* __restrict__ dst,
                          int* __restrict__ cursor, int* __restrict__ edge_src, int E) {
    int e = blockIdx.x * blockDim.x + threadIdx.x;
    if (e < E) {
        int d = dst[e];
        int pos = atomicAdd(&cursor[d], 1);
        edge_src[pos] = src[e];
    }
}

// ------------------------------------------------------- neighbor mean (CSR)
// One wave (64 lanes) per destination node; 128 features = 2 floats/lane.
__global__ void aggregate_k(const float* __restrict__ x,
                            const int* __restrict__ edge_src,
                            const int* __restrict__ offsets,
                            const int* __restrict__ counts,
                            float* __restrict__ agg, int n) {
    int wid  = (blockIdx.x * blockDim.x + threadIdx.x) >> 6;
    int lane = threadIdx.x & 63;
    if (wid >= n) return;
    int start = offsets[wid];
    int cnt   = counts[wid];
    float ax = 0.f, ay = 0.f;
    for (int base = 0; base < cnt; base += 64) {
        int valid = min(64, cnt - base);
        int s = (lane < valid) ? edge_src[start + base + lane] : 0;
        #pragma unroll 4
        for (int k = 0; k < valid; ++k) {
            int sk = __shfl(s, k);
            const float2 v = *(const float2*)(x + (size_t)sk * D + lane * 2);
            ax += v.x;
            ay += v.y;
        }
    }
    float inv = 1.0f / fmaxf((float)cnt, 1.0f);
    float2 o;
    o.x = ax * inv;
    o.y = ay * inv;
    *(float2*)(agg + (size_t)wid * D + lane * 2) = o;
}

// ----------------------------------------------------------- fused SAGE GEMM
// C[n0..n0+63][0..127] = A0 @ Ws + A1 @ Wn + b   (optional relu)
// BM=64, BN=128, BK=32, 256 threads; per-thread 8 rows x 4 cols fp32 acc.
__global__ __launch_bounds__(256)
void sage_gemm_k(const float* __restrict__ A0, const float* __restrict__ A1,
                 const float* __restrict__ Ws, const float* __restrict__ Wn,
                 const float* __restrict__ bias, float* __restrict__ C,
                 int n, int do_relu) {
    __shared__ float  As[32][64];    // [k][row]  8 KB
    __shared__ float4 Wc[32][32];    // [k][col4] 16 KB
    int t  = threadIdx.x;
    int tc = t & 31;    // col group (4 cols)
    int tr = t >> 5;    // row group (8 rows)
    int n0 = blockIdx.x * 64;

    float4 acc[8];
    #pragma unroll
    for (int r = 0; r < 8; ++r) acc[r] = make_float4(0.f, 0.f, 0.f, 0.f);

    for (int chunk = 0; chunk < 8; ++chunk) {
        const int half = chunk >> 2;
        const int k0   = (chunk & 3) * 32;
        const float* __restrict__ W = half ? Wn : Ws;
        const float* __restrict__ A = half ? A1 : A0;

        // stage W chunk: 32x128 floats = 1024 float4, 4 per thread, coalesced
        #pragma unroll
        for (int i = 0; i < 4; ++i) {
            int l  = t + 256 * i;
            int k  = l >> 5;
            int c4 = l & 31;
            Wc[k][c4] = *(const float4*)(W + (size_t)(k0 + k) * D + c4 * 4);
        }
        // stage A chunk transposed: 64 rows x 32 k = 512 float4, 2 per thread
        #pragma unroll
        for (int i = 0; i < 2; ++i) {
            int l  = t + 256 * i;
            int r  = l >> 3;
            int k4 = l & 7;
            int node = n0 + r;
            float4 v = make_float4(0.f, 0.f, 0.f, 0.f);
            if (node < n) v = *(const float4*)(A + (size_t)node * D + k0 + k4 * 4);
            As[k4 * 4 + 0][r] = v.x;
            As[k4 * 4 + 1][r] = v.y;
            As[k4 * 4 + 2][r] = v.z;
            As[k4 * 4 + 3][r] = v.w;
        }
        __syncthreads();

        #pragma unroll
        for (int k = 0; k < 32; ++k) {
            float4 w = Wc[k][tc];
            const float* ap = &As[k][tr * 8];
            float4 a0 = *(const float4*)ap;
            float4 a1 = *(const float4*)(ap + 4);
            float a[8] = {a0.x, a0.y, a0.z, a0.w, a1.x, a1.y, a1.z, a1.w};
            #pragma unroll
            for (int r = 0; r < 8; ++r) {
                acc[r].x += a[r] * w.x;
                acc[r].y += a[r] * w.y;
                acc[r].z += a[r] * w.z;
                acc[r].w += a[r] * w.w;
            }
        }
        __syncthreads();
    }

    float4 bb = *(const float4*)(bias + tc * 4);
    #pragma unroll
    for (int r = 0; r < 8; ++r) {
        int row = n0 + tr * 8 + r;
        if (row < n) {
            float4 o;
            o.x = acc[r].x + bb.x;
            o.y = acc[r].y + bb.y;
            o.z = acc[r].z + bb.z;
            o.w = acc[r].w + bb.w;
            if (do_relu) {
                o.x = fmaxf(o.x, 0.f);
                o.y = fmaxf(o.y, 0.f);
                o.z = fmaxf(o.z, 0.f);
                o.w = fmaxf(o.w, 0.f);
            }
            *(float4*)(C + (size_t)row * D + tc * 4) = o;
        }
    }
}

// ------------------------------------------------------------------- launch

extern "C" void kernel_launch(void* const* d_in, const int* in_sizes, int n_in,
                              void* d_out, int out_size, void* d_ws, size_t ws_size,
                              hipStream_t stream) {
    const float* in_feat = (const float*)d_in[0];
    const float* W1s     = (const float*)d_in[1];
    const float* W1n     = (const float*)d_in[2];
    const float* b1      = (const float*)d_in[3];
    const float* W2s     = (const float*)d_in[4];
    const float* W2n     = (const float*)d_in[5];
    const float* b2      = (const float*)d_in[6];
    const int*   src     = (const int*)d_in[7];
    const int*   dst     = (const int*)d_in[8];

    const int N = in_sizes[0] / D;
    const int E = in_sizes[7];

    // workspace layout (agg first for 16B alignment)
    float* agg      = (float*)d_ws;                 // N*D floats
    int*   counts   = (int*)(agg + (size_t)N * D);  // N
    int*   offsets  = counts + N;                   // N
    int*   cursor   = offsets + N;                  // N
    int*   blocksums= cursor + N;                   // 256
    int*   edge_src = blocksums + 256;              // E

    float* h = (float*)d_out;   // layer-1 activations live in d_out

    const int nb = (N + 1023) / 1024;   // scan blocks (98 for N=100000)

    // ---- build CSR by destination (once, reused by both layers)
    hipLaunchKernelGGL(zero_counts_k, dim3((N + 255) / 256), dim3(256), 0, stream,
                       counts, N);
    hipLaunchKernelGGL(count_deg_k, dim3((E + 255) / 256), dim3(256), 0, stream,
                       dst, counts, E);
    hipLaunchKernelGGL(scan_block_k, dim3(nb), dim3(256), 0, stream,
                       counts, offsets, blocksums, N);
    hipLaunchKernelGGL(scan_top_k, dim3(1), dim3(256), 0, stream,
                       blocksums, nb);
    hipLaunchKernelGGL(scan_add_k, dim3((N + 255) / 256), dim3(256), 0, stream,
                       offsets, cursor, blocksums, N);
    hipLaunchKernelGGL(scatter_k, dim3((E + 255) / 256), dim3(256), 0, stream,
                       src, dst, cursor, edge_src, E);

    const dim3 aggGrid((N * 64 + 255) / 256);
    const dim3 gemmGrid((N + 63) / 64);

    // ---- layer 1
    hipLaunchKernelGGL(aggregate_k, aggGrid, dim3(256), 0, stream,
                       in_feat, edge_src, offsets, counts, agg, N);
    hipLaunchKernelGGL(sage_gemm_k, gemmGrid, dim3(256), 0, stream,
                       in_feat, agg, W1s, W1n, b1, h, N, 1);

    // ---- layer 2 (in-place on d_out: each block reads only its own rows)
    hipLaunchKernelGGL(aggregate_k, aggGrid, dim3(256), 0, stream,
                       h, edge_src, offsets, counts, agg, N);
    hipLaunchKernelGGL(sage_gemm_k, gemmGrid, dim3(256), 0, stream,
                       h, agg, W2s, W2n, b2, (float*)d_out, N, 0);
}

// Round 2
// 571.065 us; speedup vs baseline: 1.2790x; 1.2790x over previous
//
#include <hip/hip_runtime.h>

#define D 128
#define NB_MAX 1024
#define PART_BLOCKS 512

using f32x4  = __attribute__((ext_vector_type(4))) float;
using short8 = __attribute__((ext_vector_type(8))) short;

// ------------------------------------------------ weight transpose + split
// Wt[n][k] (k-major, K=256: k<128 -> Ws[k][n], k>=128 -> Wn[k-128][n])
// split fp32 -> bf16 hi (truncate) + bf16 lo (truncate of remainder)
__global__ void convert_w_k(const float* __restrict__ Ws, const float* __restrict__ Wn,
                            unsigned short* __restrict__ Wt_hi,
                            unsigned short* __restrict__ Wt_lo) {
    int idx = blockIdx.x * blockDim.x + threadIdx.x;   // 0 .. 128*256-1
    if (idx >= 128 * 256) return;
    int n = idx >> 8;
    int k = idx & 255;
    float v = (k < 128) ? Ws[k * D + n] : Wn[(k - 128) * D + n];
    unsigned u = __float_as_uint(v);
    float rr = v - __uint_as_float(u & 0xFFFF0000u);
    Wt_hi[idx] = (unsigned short)(u >> 16);
    Wt_lo[idx] = (unsigned short)(__float_as_uint(rr) >> 16);
}

// ------------------------------------------------ CSR build, bucketed
__global__ void zero_buckets_k(int* __restrict__ bucket_counts, int nb) {
    int i = blockIdx.x * blockDim.x + threadIdx.x;
    if (i < nb) bucket_counts[i] = 0;
}

__global__ void bucket_count_k(const int* __restrict__ dst, int* __restrict__ bucket_counts,
                               int E, int nb) {
    __shared__ int hist[NB_MAX];
    int t = threadIdx.x;
    for (int b = t; b < nb; b += 256) hist[b] = 0;
    __syncthreads();
    for (int i = blockIdx.x * 256 + t; i < E; i += gridDim.x * 256)
        atomicAdd(&hist[dst[i] >> 9], 1);
    __syncthreads();
    for (int b = t; b < nb; b += 256) {
        int c = hist[b];
        if (c) atomicAdd(&bucket_counts[b], c);
    }
}

// single block, nb <= 1024: exclusive scan -> bucket_base[0..nb], cursor init
__global__ void bucket_scan_k(const int* __restrict__ bucket_counts,
                              int* __restrict__ bucket_base,
                              int* __restrict__ bucket_cursor, int nb) {
    __shared__ int sh[256];
    int t = threadIdx.x;
    int base = t * 4;
    int v0 = (base + 0 < nb) ? bucket_counts[base + 0] : 0;
    int v1 = (base + 1 < nb) ? bucket_counts[base + 1] : 0;
    int v2 = (base + 2 < nb) ? bucket_counts[base + 2] : 0;
    int v3 = (base + 3 < nb) ? bucket_counts[base + 3] : 0;
    int tsum = v0 + v1 + v2 + v3;
    sh[t] = tsum;
    __syncthreads();
    for (int off = 1; off < 256; off <<= 1) {
        int x = 0;
        if (t >= off) x = sh[t - off];
        __syncthreads();
        if (t >= off) sh[t] += x;
        __syncthreads();
    }
    int excl = sh[t] - tsum;
    if (base + 0 <= nb) { int e = excl;                 if (base + 0 < nb) { bucket_base[base+0] = e; bucket_cursor[base+0] = e; } }
    if (base + 0 < nb) { bucket_base[base+0] = excl;          bucket_cursor[base+0] = excl; }
    if (base + 1 < nb) { bucket_base[base+1] = excl+v0;       bucket_cursor[base+1] = excl+v0; }
    if (base + 2 < nb) { bucket_base[base+2] = excl+v0+v1;    bucket_cursor[base+2] = excl+v0+v1; }
    if (base + 3 < nb) { bucket_base[base+3] = excl+v0+v1+v2; bucket_cursor[base+3] = excl+v0+v1+v2; }
    if (t == 255) bucket_base[nb] = sh[255];
}

// partition edges into bucket-contiguous (src,dst) pairs
__global__ void partition_k(const int* __restrict__ src, const int* __restrict__ dst,
                            int* __restrict__ bucket_cursor, int2* __restrict__ pairs,
                            int E, int nb, int chunk) {
    __shared__ int hist[NB_MAX];
    __shared__ int bbase[NB_MAX];
    int t = threadIdx.x;
    int e0 = blockIdx.x * chunk;
    int e1 = min(E, e0 + chunk);
    for (int b = t; b < nb; b += 256) hist[b] = 0;
    __syncthreads();
    for (int i = e0 + t; i < e1; i += 256)
        atomicAdd(&hist[dst[i] >> 9], 1);
    __syncthreads();
    for (int b = t; b < nb; b += 256) {
        int c = hist[b];
        int bs = 0;
        if (c) bs = atomicAdd(&bucket_cursor[b], c);
        bbase[b] = bs;
        hist[b] = 0;            // reuse as local cursor
    }
    __syncthreads();
    for (int i = e0 + t; i < e1; i += 256) {
        int dd = dst[i];
        int b = dd >> 9;
        int r = atomicAdd(&hist[b], 1);
        pairs[bbase[b] + r] = make_int2(src[i], dd);
    }
}

// one block per bucket: local histogram + scan -> counts/offsets/edge_src
__global__ void build_csr_k(const int2* __restrict__ pairs,
                            const int* __restrict__ bucket_base,
                            int* __restrict__ counts, int* __restrict__ offsets,
                            int* __restrict__ edge_src, int N) {
    __shared__ int hist[512];
    __shared__ int curs[512];
    __shared__ int sh[256];
    int t = threadIdx.x;
    int b = blockIdx.x;
    int n0 = b << 9;
    int e0 = bucket_base[b];
    int e1 = bucket_base[b + 1];
    hist[t] = 0; hist[t + 256] = 0;
    __syncthreads();
    for (int i = e0 + t; i < e1; i += 256)
        atomicAdd(&hist[pairs[i].y - n0], 1);
    __syncthreads();
    int a = hist[2 * t], c = hist[2 * t + 1];
    int s2 = a + c;
    sh[t] = s2;
    __syncthreads();
    for (int off = 1; off < 256; off <<= 1) {
        int x = 0;
        if (t >= off) x = sh[t - off];
        __syncthreads();
        if (t >= off) sh[t] += x;
        __syncthreads();
    }
    int excl = sh[t] - s2;
    curs[2 * t] = excl;
    curs[2 * t + 1] = excl + a;
    int node = n0 + 2 * t;
    if (node < N)     { counts[node] = a;     offsets[node] = e0 + excl; }
    if (node + 1 < N) { counts[node + 1] = c; offsets[node + 1] = e0 + excl + a; }
    __syncthreads();
    for (int i = e0 + t; i < e1; i += 256) {
        int2 p = pairs[i];
        int pos = atomicAdd(&curs[p.y - n0], 1);
        edge_src[e0 + pos] = p.x;
    }
}

// ------------------------------------------------ neighbor mean (CSR)
// one wave per dst node; half-wave (32 lanes) x float4 covers a 512B row;
// two edges processed per inner iteration.
__global__ void aggregate_k(const float* __restrict__ x,
                            const int* __restrict__ edge_src,
                            const int* __restrict__ offsets,
                            const int* __restrict__ counts,
                            float* __restrict__ agg, int n) {
    int wid  = (blockIdx.x * blockDim.x + threadIdx.x) >> 6;
    int lane = threadIdx.x & 63;
    if (wid >= n) return;
    int half = lane >> 5;
    int sub  = lane & 31;
    int start = offsets[wid];
    int cnt   = counts[wid];
    float ax = 0.f, ay = 0.f, az = 0.f, aw = 0.f;
    for (int base = 0; base < cnt; base += 64) {
        int valid = min(64, cnt - base);
        int s = (lane < valid) ? edge_src[start + base + lane] : 0;
        int iter = (valid + 1) >> 1;
        #pragma unroll 4
        for (int k = 0; k < iter; ++k) {
            int idx = 2 * k + half;
            int row = __shfl(s, idx);
            float wgt = (idx < valid) ? 1.0f : 0.0f;
            const float4 v = *(const float4*)(x + (size_t)row * D + sub * 4);
            ax = fmaf(v.x, wgt, ax);
            ay = fmaf(v.y, wgt, ay);
            az = fmaf(v.z, wgt, az);
            aw = fmaf(v.w, wgt, aw);
        }
    }
    ax += __shfl(ax, lane ^ 32);
    ay += __shfl(ay, lane ^ 32);
    az += __shfl(az, lane ^ 32);
    aw += __shfl(aw, lane ^ 32);
    if (half == 0) {
        float inv = 1.0f / fmaxf((float)cnt, 1.0f);
        float4 o;
        o.x = ax * inv; o.y = ay * inv; o.z = az * inv; o.w = aw * inv;
        *(float4*)(agg + (size_t)wid * D + sub * 4) = o;
    }
}

// ------------------------------------------------ split-bf16 MFMA GEMM
// C[row][0..127] = A0 @ Ws + A1 @ Wn + b  (fp32 in, split-bf16 3-term MFMA)
// wave = 32 rows x 128 cols; block = 4 waves = 128 rows; no LDS.
__global__ __launch_bounds__(256)
void mfma_gemm_k(const float* __restrict__ A0, const float* __restrict__ A1,
                 const unsigned short* __restrict__ Bhi,
                 const unsigned short* __restrict__ Blo,
                 const float* __restrict__ bias,
                 float* __restrict__ C, int n, int do_relu) {
    int t = threadIdx.x;
    int w = t >> 6;
    int l = t & 63;
    int m = l & 15;          // A row within tile / B,C col within tile
    int q = l >> 4;          // quad: A/B k = q*8+j ; C row = q*4+r
    int r0 = blockIdx.x * 128 + w * 32;

    f32x4 acc[2][8];
    #pragma unroll
    for (int rt = 0; rt < 2; ++rt)
        #pragma unroll
        for (int ct = 0; ct < 8; ++ct)
            acc[rt][ct] = (f32x4){0.f, 0.f, 0.f, 0.f};

    for (int kc = 0; kc < 8; ++kc) {
        const float* __restrict__ A = (kc < 4) ? A0 : A1;
        int ka = (kc & 3) * 32;           // k offset within A matrix
        short8 ah[2], al[2];
        #pragma unroll
        for (int rt = 0; rt < 2; ++rt) {
            int row = r0 + rt * 16 + m;
            float4 v0 = make_float4(0.f, 0.f, 0.f, 0.f);
            float4 v1 = make_float4(0.f, 0.f, 0.f, 0.f);
            if (row < n) {
                const float* p = A + (size_t)row * D + ka + q * 8;
                v0 = *(const float4*)p;
                v1 = *(const float4*)(p + 4);
            }
            float f[8] = {v0.x, v0.y, v0.z, v0.w, v1.x, v1.y, v1.z, v1.w};
            short8 h, lo;
            #pragma unroll
            for (int j = 0; j < 8; ++j) {
                unsigned u = __float_as_uint(f[j]);
                h[j] = (short)(u >> 16);
                float rr = f[j] - __uint_as_float(u & 0xFFFF0000u);
                lo[j] = (short)(__float_as_uint(rr) >> 16);
            }
            ah[rt] = h;
            al[rt] = lo;
        }
        #pragma unroll
        for (int ct = 0; ct < 8; ++ct) {
            int col = ct * 16 + m;
            size_t bo = (size_t)col * 256 + kc * 32 + q * 8;
            short8 bh = *(const short8*)(Bhi + bo);
            short8 bl = *(const short8*)(Blo + bo);
            #pragma unroll
            for (int rt = 0; rt < 2; ++rt) {
                acc[rt][ct] = __builtin_amdgcn_mfma_f32_16x16x32_bf16(ah[rt], bh, acc[rt][ct], 0, 0, 0);
                acc[rt][ct] = __builtin_amdgcn_mfma_f32_16x16x32_bf16(ah[rt], bl, acc[rt][ct], 0, 0, 0);
                acc[rt][ct] = __builtin_amdgcn_mfma_f32_16x16x32_bf16(al[rt], bh, acc[rt][ct], 0, 0, 0);
            }
        }
    }
    #pragma unroll
    for (int ct = 0; ct < 8; ++ct) {
        int col = ct * 16 + m;
        float bb = bias[col];
        #pragma unroll
        for (int rt = 0; rt < 2; ++rt) {
            #pragma unroll
            for (int r = 0; r < 4; ++r) {
                int row = r0 + rt * 16 + q * 4 + r;
                if (row < n) {
                    float v = acc[rt][ct][r] + bb;
                    if (do_relu) v = fmaxf(v, 0.f);
                    C[(size_t)row * D + col] = v;
                }
            }
        }
    }
}

// ------------------------------------------------------------------- launch
extern "C" void kernel_launch(void* const* d_in, const int* in_sizes, int n_in,
                              void* d_out, int out_size, void* d_ws, size_t ws_size,
                              hipStream_t stream) {
    const float* in_feat = (const float*)d_in[0];
    const float* W1s     = (const float*)d_in[1];
    const float* W1n     = (const float*)d_in[2];
    const float* b1      = (const float*)d_in[3];
    const float* W2s     = (const float*)d_in[4];
    const float* W2n     = (const float*)d_in[5];
    const float* b2      = (const float*)d_in[6];
    const int*   src     = (const int*)d_in[7];
    const int*   dst     = (const int*)d_in[8];

    const int N  = in_sizes[0] / D;
    const int E  = in_sizes[7];
    const int NB = (N + 511) >> 9;     // buckets of 512 nodes

    // workspace layout (all 16B-aligned segment sizes)
    float* agg      = (float*)d_ws;                               // N*D f32
    int*   edge_src = (int*)(agg + (size_t)N * D);                // E
    int*   counts   = edge_src + E;                               // N
    int*   offsets  = counts + N;                                 // N
    unsigned short* Wt = (unsigned short*)(offsets + N);          // 4 * 32768
    unsigned short* Wt1_hi = Wt;
    unsigned short* Wt1_lo = Wt + 32768;
    unsigned short* Wt2_hi = Wt + 2 * 32768;
    unsigned short* Wt2_lo = Wt + 3 * 32768;
    int* bucket_counts = (int*)(Wt + 4 * 32768);                  // NB_MAX
    int* bucket_base   = bucket_counts + NB_MAX;                  // NB_MAX+1
    int* bucket_cursor = bucket_base + NB_MAX + 1;                // NB_MAX
    int2* pairs = (int2*)d_ws;   // aliases agg: consumed before agg is written

    float* h = (float*)d_out;    // layer-1 activations live in d_out

    const int chunk = (E + PART_BLOCKS - 1) / PART_BLOCKS;

    // weight transpose+split (tiny, L2-resident afterwards)
    hipLaunchKernelGGL(convert_w_k, dim3(128), dim3(256), 0, stream, W1s, W1n, Wt1_hi, Wt1_lo);
    hipLaunchKernelGGL(convert_w_k, dim3(128), dim3(256), 0, stream, W2s, W2n, Wt2_hi, Wt2_lo);

    // CSR build (bucketed counting sort by dst)
    hipLaunchKernelGGL(zero_buckets_k, dim3((NB + 255) / 256), dim3(256), 0, stream,
                       bucket_counts, NB);
    hipLaunchKernelGGL(bucket_count_k, dim3(PART_BLOCKS), dim3(256), 0, stream,
                       dst, bucket_counts, E, NB);
    hipLaunchKernelGGL(bucket_scan_k, dim3(1), dim3(256), 0, stream,
                       bucket_counts, bucket_base, bucket_cursor, NB);
    hipLaunchKernelGGL(partition_k, dim3(PART_BLOCKS), dim3(256), 0, stream,
                       src, dst, bucket_cursor, pairs, E, NB, chunk);
    hipLaunchKernelGGL(build_csr_k, dim3(NB), dim3(256), 0, stream,
                       pairs, bucket_base, counts, offsets, edge_src, N);

    const dim3 aggGrid(((size_t)N * 64 + 255) / 256);
    const dim3 gemmGrid((N + 127) / 128);

    // layer 1
    hipLaunchKernelGGL(aggregate_k, aggGrid, dim3(256), 0, stream,
                       in_feat, edge_src, offsets, counts, agg, N);
    hipLaunchKernelGGL(mfma_gemm_k, gemmGrid, dim3(256), 0, stream,
                       in_feat, agg, Wt1_hi, Wt1_lo, b1, h, N, 1);

    // layer 2 (in-place on d_out: each block reads only its own rows)
    hipLaunchKernelGGL(aggregate_k, aggGrid, dim3(256), 0, stream,
                       h, edge_src, offsets, counts, agg, N);
    hipLaunchKernelGGL(mfma_gemm_k, gemmGrid, dim3(256), 0, stream,
                       h, agg, Wt2_hi, Wt2_lo, b2, (float*)d_out, N, 0);
}

// Round 3
// 537.377 us; speedup vs baseline: 1.3592x; 1.0627x over previous
//
#include <hip/hip_runtime.h>
#include <hip/hip_fp16.h>

#define D 128
#define NB_MAX 1024
#define PART_BLOCKS 512

using f32x4  = __attribute__((ext_vector_type(4))) float;
using short8 = __attribute__((ext_vector_type(8))) short;

// ------------------------------------------------ weight transpose + split
__global__ void convert_w_k(const float* __restrict__ Ws, const float* __restrict__ Wn,
                            unsigned short* __restrict__ Wt_hi,
                            unsigned short* __restrict__ Wt_lo) {
    int idx = blockIdx.x * blockDim.x + threadIdx.x;   // 0 .. 128*256-1
    if (idx >= 128 * 256) return;
    int n = idx >> 8;
    int k = idx & 255;
    float v = (k < 128) ? Ws[k * D + n] : Wn[(k - 128) * D + n];
    unsigned u = __float_as_uint(v);
    float rr = v - __uint_as_float(u & 0xFFFF0000u);
    Wt_hi[idx] = (unsigned short)(u >> 16);
    Wt_lo[idx] = (unsigned short)(__float_as_uint(rr) >> 16);
}

// ------------------------------------------------ x -> fp16
__global__ void convert_x_k(const float* __restrict__ x, __half* __restrict__ y, int n4) {
    int i = blockIdx.x * blockDim.x + threadIdx.x;
    if (i < n4) {
        float4 v = *(const float4*)(x + (size_t)i * 4);
        __half2 h0 = __floats2half2_rn(v.x, v.y);
        __half2 h1 = __floats2half2_rn(v.z, v.w);
        __half2* o = (__half2*)(y + (size_t)i * 4);
        o[0] = h0; o[1] = h1;
    }
}

// ------------------------------------------------ CSR build, bucketed (256 nodes/bucket)
__global__ void zero_buckets_k(int* __restrict__ bucket_counts, int nb) {
    int i = blockIdx.x * blockDim.x + threadIdx.x;
    if (i < nb) bucket_counts[i] = 0;
}

__global__ void bucket_count_k(const int* __restrict__ dst, int* __restrict__ bucket_counts,
                               int E, int nb) {
    __shared__ int hist[NB_MAX];
    int t = threadIdx.x;
    for (int b = t; b < nb; b += 256) hist[b] = 0;
    __syncthreads();
    for (int i = blockIdx.x * 256 + t; i < E; i += gridDim.x * 256)
        atomicAdd(&hist[dst[i] >> 8], 1);
    __syncthreads();
    for (int b = t; b < nb; b += 256) {
        int c = hist[b];
        if (c) atomicAdd(&bucket_counts[b], c);
    }
}

// single block, nb <= 1024: exclusive scan -> bucket_base[0..nb], cursor init
__global__ void bucket_scan_k(const int* __restrict__ bucket_counts,
                              int* __restrict__ bucket_base,
                              int* __restrict__ bucket_cursor, int nb) {
    __shared__ int sh[256];
    int t = threadIdx.x;
    int base = t * 4;
    int v0 = (base + 0 < nb) ? bucket_counts[base + 0] : 0;
    int v1 = (base + 1 < nb) ? bucket_counts[base + 1] : 0;
    int v2 = (base + 2 < nb) ? bucket_counts[base + 2] : 0;
    int v3 = (base + 3 < nb) ? bucket_counts[base + 3] : 0;
    int tsum = v0 + v1 + v2 + v3;
    sh[t] = tsum;
    __syncthreads();
    for (int off = 1; off < 256; off <<= 1) {
        int x = 0;
        if (t >= off) x = sh[t - off];
        __syncthreads();
        if (t >= off) sh[t] += x;
        __syncthreads();
    }
    int excl = sh[t] - tsum;
    if (base + 0 < nb) { bucket_base[base+0] = excl;          bucket_cursor[base+0] = excl; }
    if (base + 1 < nb) { bucket_base[base+1] = excl+v0;       bucket_cursor[base+1] = excl+v0; }
    if (base + 2 < nb) { bucket_base[base+2] = excl+v0+v1;    bucket_cursor[base+2] = excl+v0+v1; }
    if (base + 3 < nb) { bucket_base[base+3] = excl+v0+v1+v2; bucket_cursor[base+3] = excl+v0+v1+v2; }
    if (t == 255) bucket_base[nb] = sh[255];
}

// partition edges into bucket-contiguous packed (localdst<<17 | src)
__global__ void partition_k(const int* __restrict__ src, const int* __restrict__ dst,
                            int* __restrict__ bucket_cursor, unsigned* __restrict__ pairs,
                            int E, int nb, int chunk) {
    __shared__ int hist[NB_MAX];
    __shared__ int bbase[NB_MAX];
    int t = threadIdx.x;
    int e0 = blockIdx.x * chunk;
    int e1 = min(E, e0 + chunk);
    for (int b = t; b < nb; b += 256) hist[b] = 0;
    __syncthreads();
    for (int i = e0 + t; i < e1; i += 256)
        atomicAdd(&hist[dst[i] >> 8], 1);
    __syncthreads();
    for (int b = t; b < nb; b += 256) {
        int c = hist[b];
        int bs = 0;
        if (c) bs = atomicAdd(&bucket_cursor[b], c);
        bbase[b] = bs;
        hist[b] = 0;            // reuse as local cursor
    }
    __syncthreads();
    for (int i = e0 + t; i < e1; i += 256) {
        int dd = dst[i];
        int b = dd >> 8;
        int r = atomicAdd(&hist[b], 1);
        pairs[bbase[b] + r] = ((unsigned)(dd & 255) << 17) | (unsigned)src[i];
    }
}

// one block per 256-node bucket
__global__ void build_csr_k(const unsigned* __restrict__ pairs,
                            const int* __restrict__ bucket_base,
                            int* __restrict__ counts, int* __restrict__ offsets,
                            int* __restrict__ edge_src, int N) {
    __shared__ int hist[256];
    __shared__ int curs[256];
    __shared__ int sh[256];
    int t = threadIdx.x;
    int b = blockIdx.x;
    int n0 = b << 8;
    int e0 = bucket_base[b];
    int e1 = bucket_base[b + 1];
    hist[t] = 0;
    __syncthreads();
    for (int i = e0 + t; i < e1; i += 256)
        atomicAdd(&hist[pairs[i] >> 17], 1);
    __syncthreads();
    int c = hist[t];
    sh[t] = c;
    __syncthreads();
    for (int off = 1; off < 256; off <<= 1) {
        int x = 0;
        if (t >= off) x = sh[t - off];
        __syncthreads();
        if (t >= off) sh[t] += x;
        __syncthreads();
    }
    int excl = sh[t] - c;
    curs[t] = excl;
    int node = n0 + t;
    if (node < N) { counts[node] = c; offsets[node] = e0 + excl; }
    __syncthreads();
    for (int i = e0 + t; i < e1; i += 256) {
        unsigned p = pairs[i];
        int pos = atomicAdd(&curs[p >> 17], 1);
        edge_src[e0 + pos] = (int)(p & 0x1FFFFu);
    }
}

// ------------------------------------------------ neighbor mean, fp16 gather
// one wave per dst node; 16 lanes x float4 (8 halves) per row; 4 edges/iter.
__global__ void aggregate_f16_k(const __half* __restrict__ x,
                                const int* __restrict__ edge_src,
                                const int* __restrict__ offsets,
                                const int* __restrict__ counts,
                                float* __restrict__ agg, int n) {
    int wid  = (blockIdx.x * blockDim.x + threadIdx.x) >> 6;
    int lane = threadIdx.x & 63;
    if (wid >= n) return;
    int sg  = lane >> 4;     // 0..3: which edge of the quad
    int sub = lane & 15;     // 16 lanes cover one 256B row
    int start = offsets[wid];
    int cnt   = counts[wid];
    float acc[8] = {0.f, 0.f, 0.f, 0.f, 0.f, 0.f, 0.f, 0.f};
    for (int base = 0; base < cnt; base += 64) {
        int valid = min(64, cnt - base);
        int s = (lane < valid) ? edge_src[start + base + lane] : 0;
        int iter = (valid + 3) >> 2;
        #pragma unroll 2
        for (int k = 0; k < iter; ++k) {
            int idx = 4 * k + sg;
            int row = __shfl(s, idx);
            float wgt = (idx < valid) ? 1.0f : 0.0f;
            float4 raw = *(const float4*)(x + (size_t)row * D + sub * 8);
            const __half2* hp = (const __half2*)&raw;
            #pragma unroll
            for (int j = 0; j < 4; ++j) {
                float2 f = __half22float2(hp[j]);
                acc[2 * j]     = fmaf(f.x, wgt, acc[2 * j]);
                acc[2 * j + 1] = fmaf(f.y, wgt, acc[2 * j + 1]);
            }
        }
    }
    #pragma unroll
    for (int j = 0; j < 8; ++j) {
        acc[j] += __shfl(acc[j], lane ^ 16);
        acc[j] += __shfl(acc[j], lane ^ 32);
    }
    if (sg == 0) {
        float inv = 1.0f / fmaxf((float)cnt, 1.0f);
        float4 o0 = make_float4(acc[0]*inv, acc[1]*inv, acc[2]*inv, acc[3]*inv);
        float4 o1 = make_float4(acc[4]*inv, acc[5]*inv, acc[6]*inv, acc[7]*inv);
        float* op = agg + (size_t)wid * D + sub * 8;
        *(float4*)op = o0;
        *(float4*)(op + 4) = o1;
    }
}

// fp32 fallback (if workspace too small for fp16 shadow buffers)
__global__ void aggregate_f32_k(const float* __restrict__ x,
                                const int* __restrict__ edge_src,
                                const int* __restrict__ offsets,
                                const int* __restrict__ counts,
                                float* __restrict__ agg, int n) {
    int wid  = (blockIdx.x * blockDim.x + threadIdx.x) >> 6;
    int lane = threadIdx.x & 63;
    if (wid >= n) return;
    int half = lane >> 5;
    int sub  = lane & 31;
    int start = offsets[wid];
    int cnt   = counts[wid];
    float ax = 0.f, ay = 0.f, az = 0.f, aw = 0.f;
    for (int base = 0; base < cnt; base += 64) {
        int valid = min(64, cnt - base);
        int s = (lane < valid) ? edge_src[start + base + lane] : 0;
        int iter = (valid + 1) >> 1;
        #pragma unroll 4
        for (int k = 0; k < iter; ++k) {
            int idx = 2 * k + half;
            int row = __shfl(s, idx);
            float wgt = (idx < valid) ? 1.0f : 0.0f;
            const float4 v = *(const float4*)(x + (size_t)row * D + sub * 4);
            ax = fmaf(v.x, wgt, ax);
            ay = fmaf(v.y, wgt, ay);
            az = fmaf(v.z, wgt, az);
            aw = fmaf(v.w, wgt, aw);
        }
    }
    ax += __shfl(ax, lane ^ 32);
    ay += __shfl(ay, lane ^ 32);
    az += __shfl(az, lane ^ 32);
    aw += __shfl(aw, lane ^ 32);
    if (half == 0) {
        float inv = 1.0f / fmaxf((float)cnt, 1.0f);
        float4 o;
        o.x = ax * inv; o.y = ay * inv; o.z = az * inv; o.w = aw * inv;
        *(float4*)(agg + (size_t)wid * D + sub * 4) = o;
    }
}

// ------------------------------------------------ split-bf16 MFMA GEMM
// C = A0 @ Ws + A1 @ Wn + b; optional relu; optional fp16 shadow of C.
__global__ __launch_bounds__(256)
void mfma_gemm_k(const float* __restrict__ A0, const float* __restrict__ A1,
                 const unsigned short* __restrict__ Bhi,
                 const unsigned short* __restrict__ Blo,
                 const float* __restrict__ bias,
                 float* __restrict__ C, __half* __restrict__ Csh,
                 int n, int do_relu) {
    int t = threadIdx.x;
    int w = t >> 6;
    int l = t & 63;
    int m = l & 15;          // A row within tile / B,C col within tile
    int q = l >> 4;          // quad
    int r0 = blockIdx.x * 128 + w * 32;

    f32x4 acc[2][8];
    #pragma unroll
    for (int rt = 0; rt < 2; ++rt)
        #pragma unroll
        for (int ct = 0; ct < 8; ++ct)
            acc[rt][ct] = (f32x4){0.f, 0.f, 0.f, 0.f};

    for (int kc = 0; kc < 8; ++kc) {
        const float* __restrict__ A = (kc < 4) ? A0 : A1;
        int ka = (kc & 3) * 32;
        short8 ah[2], al[2];
        #pragma unroll
        for (int rt = 0; rt < 2; ++rt) {
            int row = r0 + rt * 16 + m;
            float4 v0 = make_float4(0.f, 0.f, 0.f, 0.f);
            float4 v1 = make_float4(0.f, 0.f, 0.f, 0.f);
            if (row < n) {
                const float* p = A + (size_t)row * D + ka + q * 8;
                v0 = *(const float4*)p;
                v1 = *(const float4*)(p + 4);
            }
            float f[8] = {v0.x, v0.y, v0.z, v0.w, v1.x, v1.y, v1.z, v1.w};
            short8 h, lo;
            #pragma unroll
            for (int j = 0; j < 8; ++j) {
                unsigned u = __float_as_uint(f[j]);
                h[j] = (short)(u >> 16);
                float rr = f[j] - __uint_as_float(u & 0xFFFF0000u);
                lo[j] = (short)(__float_as_uint(rr) >> 16);
            }
            ah[rt] = h;
            al[rt] = lo;
        }
        #pragma unroll
        for (int ct = 0; ct < 8; ++ct) {
            int col = ct * 16 + m;
            size_t bo = (size_t)col * 256 + kc * 32 + q * 8;
            short8 bh = *(const short8*)(Bhi + bo);
            short8 bl = *(const short8*)(Blo + bo);
            #pragma unroll
            for (int rt = 0; rt < 2; ++rt) {
                acc[rt][ct] = __builtin_amdgcn_mfma_f32_16x16x32_bf16(ah[rt], bh, acc[rt][ct], 0, 0, 0);
                acc[rt][ct] = __builtin_amdgcn_mfma_f32_16x16x32_bf16(ah[rt], bl, acc[rt][ct], 0, 0, 0);
                acc[rt][ct] = __builtin_amdgcn_mfma_f32_16x16x32_bf16(al[rt], bh, acc[rt][ct], 0, 0, 0);
            }
        }
    }
    bool do_sh = (Csh != nullptr);
    #pragma unroll
    for (int ct = 0; ct < 8; ++ct) {
        int col = ct * 16 + m;
        float bb = bias[col];
        #pragma unroll
        for (int rt = 0; rt < 2; ++rt) {
            #pragma unroll
            for (int r = 0; r < 4; ++r) {
                int row = r0 + rt * 16 + q * 4 + r;
                if (row < n) {
                    float v = acc[rt][ct][r] + bb;
                    if (do_relu) v = fmaxf(v, 0.f);
                    C[(size_t)row * D + col] = v;
                    if (do_sh) Csh[(size_t)row * D + col] = __float2half(v);
                }
            }
        }
    }
}

// ------------------------------------------------------------------- launch
extern "C" void kernel_launch(void* const* d_in, const int* in_sizes, int n_in,
                              void* d_out, int out_size, void* d_ws, size_t ws_size,
                              hipStream_t stream) {
    const float* in_feat = (const float*)d_in[0];
    const float* W1s     = (const float*)d_in[1];
    const float* W1n     = (const float*)d_in[2];
    const float* b1      = (const float*)d_in[3];
    const float* W2s     = (const float*)d_in[4];
    const float* W2n     = (const float*)d_in[5];
    const float* b2      = (const float*)d_in[6];
    const int*   src     = (const int*)d_in[7];
    const int*   dst     = (const int*)d_in[8];

    const int N  = in_sizes[0] / D;
    const int E  = in_sizes[7];
    const int NB = (N + 255) >> 8;     // 256-node buckets

    // workspace layout
    char* base = (char*)d_ws;
    size_t off = 0;
    float* agg      = (float*)(base + off); off += (size_t)N * D * 4;
    int*   edge_src = (int*)(base + off);   off += (size_t)E * 4;
    int*   counts   = (int*)(base + off);   off += (size_t)N * 4;
    int*   offsets  = (int*)(base + off);   off += (size_t)N * 4;
    unsigned short* Wt = (unsigned short*)(base + off); off += 4 * 32768 * 2;
    unsigned short* Wt1_hi = Wt;
    unsigned short* Wt1_lo = Wt + 32768;
    unsigned short* Wt2_hi = Wt + 2 * 32768;
    unsigned short* Wt2_lo = Wt + 3 * 32768;
    int* bucket_counts = (int*)(base + off); off += NB_MAX * 4;
    int* bucket_base   = (int*)(base + off); off += (NB_MAX + 1) * 4;
    int* bucket_cursor = (int*)(base + off); off += NB_MAX * 4;
    off = (off + 15) & ~(size_t)15;
    __half* xh16 = (__half*)(base + off);    // shared x16 (layer1) / h16 (layer2)
    size_t need16 = off + (size_t)N * D * 2;
    bool use16 = (need16 <= ws_size);

    unsigned* pairs = (unsigned*)d_ws;  // aliases agg (consumed before agg written)

    float* h = (float*)d_out;           // layer-1 activations live in d_out

    const int chunk = (E + PART_BLOCKS - 1) / PART_BLOCKS;

    // weight transpose+split
    hipLaunchKernelGGL(convert_w_k, dim3(128), dim3(256), 0, stream, W1s, W1n, Wt1_hi, Wt1_lo);
    hipLaunchKernelGGL(convert_w_k, dim3(128), dim3(256), 0, stream, W2s, W2n, Wt2_hi, Wt2_lo);
    if (use16) {
        int n4 = (N * D) / 4;
        hipLaunchKernelGGL(convert_x_k, dim3((n4 + 255) / 256), dim3(256), 0, stream,
                           in_feat, xh16, n4);
    }

    // CSR build (bucketed counting sort by dst)
    hipLaunchKernelGGL(zero_buckets_k, dim3((NB + 255) / 256), dim3(256), 0, stream,
                       bucket_counts, NB);
    hipLaunchKernelGGL(bucket_count_k, dim3(PART_BLOCKS), dim3(256), 0, stream,
                       dst, bucket_counts, E, NB);
    hipLaunchKernelGGL(bucket_scan_k, dim3(1), dim3(256), 0, stream,
                       bucket_counts, bucket_base, bucket_cursor, NB);
    hipLaunchKernelGGL(partition_k, dim3(PART_BLOCKS), dim3(256), 0, stream,
                       src, dst, bucket_cursor, pairs, E, NB, chunk);
    hipLaunchKernelGGL(build_csr_k, dim3(NB), dim3(256), 0, stream,
                       pairs, bucket_base, counts, offsets, edge_src, N);

    const dim3 aggGrid(((size_t)N * 64 + 255) / 256);
    const dim3 gemmGrid((N + 127) / 128);

    if (use16) {
        // layer 1
        hipLaunchKernelGGL(aggregate_f16_k, aggGrid, dim3(256), 0, stream,
                           xh16, edge_src, offsets, counts, agg, N);
        hipLaunchKernelGGL(mfma_gemm_k, gemmGrid, dim3(256), 0, stream,
                           in_feat, agg, Wt1_hi, Wt1_lo, b1, h, xh16, N, 1);
        // layer 2 (h16 shadow written by GEMM-1 into xh16)
        hipLaunchKernelGGL(aggregate_f16_k, aggGrid, dim3(256), 0, stream,
                           xh16, edge_src, offsets, counts, agg, N);
        hipLaunchKernelGGL(mfma_gemm_k, gemmGrid, dim3(256), 0, stream,
                           h, agg, Wt2_hi, Wt2_lo, b2, (float*)d_out, (half*)nullptr, N, 0);
    } else {
        hipLaunchKernelGGL(aggregate_f32_k, aggGrid, dim3(256), 0, stream,
                           in_feat, edge_src, offsets, counts, agg, N);
        hipLaunchKernelGGL(mfma_gemm_k, gemmGrid, dim3(256), 0, stream,
                           in_feat, agg, Wt1_hi, Wt1_lo, b1, h, (half*)nullptr, N, 1);
        hipLaunchKernelGGL(aggregate_f32_k, aggGrid, dim3(256), 0, stream,
                           h, edge_src, offsets, counts, agg, N);
        hipLaunchKernelGGL(mfma_gemm_k, gemmGrid, dim3(256), 0, stream,
                           h, agg, Wt2_hi, Wt2_lo, b2, (float*)d_out, (half*)nullptr, N, 0);
    }
}

// Round 4
// 390.984 us; speedup vs baseline: 1.8681x; 1.3744x over previous
//
#include <hip/hip_runtime.h>
#include <hip/hip_fp16.h>

#define D 128
#define NB_MAX 1024
#define PART_BLOCKS 512

using f32x4  = __attribute__((ext_vector_type(4))) float;
using half8  = __attribute__((ext_vector_type(8))) _Float16;
using short8 = __attribute__((ext_vector_type(8))) short;

#define AS1(p) ((const __attribute__((address_space(1))) void*)(p))
#define AS3(p) ((__attribute__((address_space(3))) void*)(p))

// ------------------------------------------------ weight convert: fp32 -> f16 hi/lo planes
// Wg layout (halves): (((kc*2 + plane)*4 + q)*128 + col)*8 + j
//   k = kc*32 + q*8 + j ; plane 0 = f16(v), plane 1 = f16(v - hi)
// Each 16KB kc-chunk is contiguous -> global_load_lds staging; LDS reads are
// 2-way-bank-aliased only (free).
__global__ void convert_w_k(const float* __restrict__ Ws, const float* __restrict__ Wn,
                            unsigned short* __restrict__ Wg) {
    int idx = blockIdx.x * blockDim.x + threadIdx.x;   // 0 .. 128*256-1
    if (idx >= 128 * 256) return;
    int col = idx >> 8;
    int k   = idx & 255;
    float v = (k < 128) ? Ws[k * D + col] : Wn[(k - 128) * D + col];
    _Float16 hv = (_Float16)v;
    _Float16 lv = (_Float16)(v - (float)hv);
    int kc = k >> 5, q = (k >> 3) & 3, j = k & 7;
    Wg[(((kc * 2 + 0) * 4 + q) * 128 + col) * 8 + j] = *(unsigned short*)&hv;
    Wg[(((kc * 2 + 1) * 4 + q) * 128 + col) * 8 + j] = *(unsigned short*)&lv;
}

// ------------------------------------------------ x -> fp16
__global__ void convert_x_k(const float* __restrict__ x, __half* __restrict__ y, int n4) {
    int i = blockIdx.x * blockDim.x + threadIdx.x;
    if (i < n4) {
        float4 v = *(const float4*)(x + (size_t)i * 4);
        __half2 h0 = __floats2half2_rn(v.x, v.y);
        __half2 h1 = __floats2half2_rn(v.z, v.w);
        __half2* o = (__half2*)(y + (size_t)i * 4);
        o[0] = h0; o[1] = h1;
    }
}

// ------------------------------------------------ CSR build, bucketed (256 nodes/bucket)
__global__ void zero_buckets_k(int* __restrict__ bucket_counts, int nb) {
    int i = blockIdx.x * blockDim.x + threadIdx.x;
    if (i < nb) bucket_counts[i] = 0;
}

__global__ void bucket_count_k(const int* __restrict__ dst, int* __restrict__ bucket_counts,
                               int E, int nb) {
    __shared__ int hist[NB_MAX];
    int t = threadIdx.x;
    for (int b = t; b < nb; b += 256) hist[b] = 0;
    __syncthreads();
    for (int i = blockIdx.x * 256 + t; i < E; i += gridDim.x * 256)
        atomicAdd(&hist[dst[i] >> 8], 1);
    __syncthreads();
    for (int b = t; b < nb; b += 256) {
        int c = hist[b];
        if (c) atomicAdd(&bucket_counts[b], c);
    }
}

__global__ void bucket_scan_k(const int* __restrict__ bucket_counts,
                              int* __restrict__ bucket_base,
                              int* __restrict__ bucket_cursor, int nb) {
    __shared__ int sh[256];
    int t = threadIdx.x;
    int base = t * 4;
    int v0 = (base + 0 < nb) ? bucket_counts[base + 0] : 0;
    int v1 = (base + 1 < nb) ? bucket_counts[base + 1] : 0;
    int v2 = (base + 2 < nb) ? bucket_counts[base + 2] : 0;
    int v3 = (base + 3 < nb) ? bucket_counts[base + 3] : 0;
    int tsum = v0 + v1 + v2 + v3;
    sh[t] = tsum;
    __syncthreads();
    for (int off = 1; off < 256; off <<= 1) {
        int x = 0;
        if (t >= off) x = sh[t - off];
        __syncthreads();
        if (t >= off) sh[t] += x;
        __syncthreads();
    }
    int excl = sh[t] - tsum;
    if (base + 0 < nb) { bucket_base[base+0] = excl;          bucket_cursor[base+0] = excl; }
    if (base + 1 < nb) { bucket_base[base+1] = excl+v0;       bucket_cursor[base+1] = excl+v0; }
    if (base + 2 < nb) { bucket_base[base+2] = excl+v0+v1;    bucket_cursor[base+2] = excl+v0+v1; }
    if (base + 3 < nb) { bucket_base[base+3] = excl+v0+v1+v2; bucket_cursor[base+3] = excl+v0+v1+v2; }
    if (t == 255) bucket_base[nb] = sh[255];
}

__global__ void partition_k(const int* __restrict__ src, const int* __restrict__ dst,
                            int* __restrict__ bucket_cursor, unsigned* __restrict__ pairs,
                            int E, int nb, int chunk) {
    __shared__ int hist[NB_MAX];
    __shared__ int bbase[NB_MAX];
    int t = threadIdx.x;
    int e0 = blockIdx.x * chunk;
    int e1 = min(E, e0 + chunk);
    for (int b = t; b < nb; b += 256) hist[b] = 0;
    __syncthreads();
    for (int i = e0 + t; i < e1; i += 256)
        atomicAdd(&hist[dst[i] >> 8], 1);
    __syncthreads();
    for (int b = t; b < nb; b += 256) {
        int c = hist[b];
        int bs = 0;
        if (c) bs = atomicAdd(&bucket_cursor[b], c);
        bbase[b] = bs;
        hist[b] = 0;            // reuse as local cursor
    }
    __syncthreads();
    for (int i = e0 + t; i < e1; i += 256) {
        int dd = dst[i];
        int b = dd >> 8;
        int r = atomicAdd(&hist[b], 1);
        pairs[bbase[b] + r] = ((unsigned)(dd & 255) << 17) | (unsigned)src[i];
    }
}

__global__ void build_csr_k(const unsigned* __restrict__ pairs,
                            const int* __restrict__ bucket_base,
                            int* __restrict__ counts, int* __restrict__ offsets,
                            int* __restrict__ edge_src, int N) {
    __shared__ int hist[256];
    __shared__ int curs[256];
    __shared__ int sh[256];
    int t = threadIdx.x;
    int b = blockIdx.x;
    int n0 = b << 8;
    int e0 = bucket_base[b];
    int e1 = bucket_base[b + 1];
    hist[t] = 0;
    __syncthreads();
    for (int i = e0 + t; i < e1; i += 256)
        atomicAdd(&hist[pairs[i] >> 17], 1);
    __syncthreads();
    int c = hist[t];
    sh[t] = c;
    __syncthreads();
    for (int off = 1; off < 256; off <<= 1) {
        int x = 0;
        if (t >= off) x = sh[t - off];
        __syncthreads();
        if (t >= off) sh[t] += x;
        __syncthreads();
    }
    int excl = sh[t] - c;
    curs[t] = excl;
    int node = n0 + t;
    if (node < N) { counts[node] = c; offsets[node] = e0 + excl; }
    __syncthreads();
    for (int i = e0 + t; i < e1; i += 256) {
        unsigned p = pairs[i];
        int pos = atomicAdd(&curs[p >> 17], 1);
        edge_src[e0 + pos] = (int)(p & 0x1FFFFu);
    }
}

// ------------------------------------------------ neighbor mean, fp16 in/out
// one wave per dst node; 16 lanes x 16B per row; 4 edges/iter.
__global__ void aggregate_f16_k(const __half* __restrict__ x,
                                const int* __restrict__ edge_src,
                                const int* __restrict__ offsets,
                                const int* __restrict__ counts,
                                __half* __restrict__ agg, int n) {
    int wid  = (blockIdx.x * blockDim.x + threadIdx.x) >> 6;
    int lane = threadIdx.x & 63;
    if (wid >= n) return;
    int sg  = lane >> 4;     // 0..3: which edge of the quad
    int sub = lane & 15;     // 16 lanes cover one 256B row
    int start = offsets[wid];
    int cnt   = counts[wid];
    float acc[8] = {0.f, 0.f, 0.f, 0.f, 0.f, 0.f, 0.f, 0.f};
    for (int base = 0; base < cnt; base += 64) {
        int valid = min(64, cnt - base);
        int s = (lane < valid) ? edge_src[start + base + lane] : 0;
        int iter = (valid + 3) >> 2;
        #pragma unroll 2
        for (int k = 0; k < iter; ++k) {
            int idx = 4 * k + sg;
            int row = __shfl(s, idx);
            float wgt = (idx < valid) ? 1.0f : 0.0f;
            float4 raw = *(const float4*)(x + (size_t)row * D + sub * 8);
            const __half2* hp = (const __half2*)&raw;
            #pragma unroll
            for (int j = 0; j < 4; ++j) {
                float2 f = __half22float2(hp[j]);
                acc[2 * j]     = fmaf(f.x, wgt, acc[2 * j]);
                acc[2 * j + 1] = fmaf(f.y, wgt, acc[2 * j + 1]);
            }
        }
    }
    #pragma unroll
    for (int j = 0; j < 8; ++j) {
        acc[j] += __shfl(acc[j], lane ^ 16);
        acc[j] += __shfl(acc[j], lane ^ 32);
    }
    if (sg == 0) {
        float inv = 1.0f / fmaxf((float)cnt, 1.0f);
        union { __half2 h2[4]; short8 s8; } u;
        #pragma unroll
        for (int j = 0; j < 4; ++j)
            u.h2[j] = __floats2half2_rn(acc[2 * j] * inv, acc[2 * j + 1] * inv);
        *(short8*)(agg + (size_t)wid * D + sub * 8) = u.s8;
    }
}

// ------------------------------------------------ fp16 2-term MFMA GEMM, LDS-staged B
// C = A0 @ W[:128] + A1 @ W[128:] + b  with W = Whi + Wlo (f16 split, exact)
// block = 256 thr = 4 waves = 128 rows; K-loop: stage 16KB B-chunk via
// global_load_lds(16B), m97 2-barrier structure; A direct global->VGPR.
// out_mode 1: relu + fp16 store only (layer 1); 0: fp32 store (layer 2).
__global__ __launch_bounds__(256)
void mfma_gemm_k(const _Float16* __restrict__ A0, const _Float16* __restrict__ A1,
                 const unsigned short* __restrict__ Wg,
                 const float* __restrict__ bias,
                 float* __restrict__ C, __half* __restrict__ Ch,
                 int n, int out_mode) {
    __shared__ __align__(16) unsigned short lds_b[8192];   // 16 KB
    int t = threadIdx.x;
    int w = t >> 6;
    int l = t & 63;
    int m = l & 15;          // A row within tile / B,C col within tile
    int q = l >> 4;          // quad
    int r0 = blockIdx.x * 128 + w * 32;

    f32x4 acc[2][8];
    #pragma unroll
    for (int rt = 0; rt < 2; ++rt)
        #pragma unroll
        for (int ct = 0; ct < 8; ++ct)
            acc[rt][ct] = (f32x4){0.f, 0.f, 0.f, 0.f};

    for (int kc = 0; kc < 8; ++kc) {
        // async stage B chunk (16 KB contiguous) into LDS
        const unsigned short* gk = Wg + (size_t)kc * 8192;
        #pragma unroll
        for (int i = 0; i < 4; ++i) {
            int e = i * 256 + t;
            __builtin_amdgcn_global_load_lds(AS1(gk + e * 8), AS3(lds_b + e * 8), 16, 0, 0);
        }
        // A fragments (fp16, 16B each) straight from global
        const _Float16* __restrict__ A = (kc < 4) ? A0 : A1;
        int ka = (kc & 3) * 32;
        half8 a[2];
        #pragma unroll
        for (int rt = 0; rt < 2; ++rt) {
            int row = r0 + rt * 16 + m;
            half8 v = (half8){0, 0, 0, 0, 0, 0, 0, 0};
            if (row < n) v = *(const half8*)(A + (size_t)row * D + ka + q * 8);
            a[rt] = v;
        }
        __syncthreads();     // drains global_load_lds (vmcnt 0) + barrier

        #pragma unroll
        for (int ct = 0; ct < 8; ++ct) {
            half8 bh = *(const half8*)&lds_b[(size_t)(q * 128 + ct * 16 + m) * 8];
            half8 bl = *(const half8*)&lds_b[(size_t)((4 + q) * 128 + ct * 16 + m) * 8];
            #pragma unroll
            for (int rt = 0; rt < 2; ++rt) {
                acc[rt][ct] = __builtin_amdgcn_mfma_f32_16x16x32_f16(a[rt], bh, acc[rt][ct], 0, 0, 0);
                acc[rt][ct] = __builtin_amdgcn_mfma_f32_16x16x32_f16(a[rt], bl, acc[rt][ct], 0, 0, 0);
            }
        }
        __syncthreads();     // LDS reads done before next stage overwrites
    }

    #pragma unroll
    for (int ct = 0; ct < 8; ++ct) {
        int col = ct * 16 + m;
        float bb = bias[col];
        #pragma unroll
        for (int rt = 0; rt < 2; ++rt) {
            #pragma unroll
            for (int r = 0; r < 4; ++r) {
                int row = r0 + rt * 16 + q * 4 + r;
                if (row < n) {
                    float v = acc[rt][ct][r] + bb;
                    if (out_mode) {
                        v = fmaxf(v, 0.f);
                        Ch[(size_t)row * D + col] = __float2half(v);
                    } else {
                        C[(size_t)row * D + col] = v;
                    }
                }
            }
        }
    }
}

// ------------------------------------------------------------------- launch
extern "C" void kernel_launch(void* const* d_in, const int* in_sizes, int n_in,
                              void* d_out, int out_size, void* d_ws, size_t ws_size,
                              hipStream_t stream) {
    const float* in_feat = (const float*)d_in[0];
    const float* W1s     = (const float*)d_in[1];
    const float* W1n     = (const float*)d_in[2];
    const float* b1      = (const float*)d_in[3];
    const float* W2s     = (const float*)d_in[4];
    const float* W2n     = (const float*)d_in[5];
    const float* b2      = (const float*)d_in[6];
    const int*   src     = (const int*)d_in[7];
    const int*   dst     = (const int*)d_in[8];

    const int N  = in_sizes[0] / D;
    const int E  = in_sizes[7];
    const int NB = (N + 255) >> 8;     // 256-node buckets

    // workspace layout
    char* base = (char*)d_ws;
    size_t off = 0;
    __half* agg16 = (__half*)(base + off); off += (size_t)N * D * 2;   // neighbor means
    __half* xh16  = (__half*)(base + off); off += (size_t)N * D * 2;   // x16, then h16 (in-place)
    int* edge_src = (int*)(base + off);    off += (size_t)E * 4;
    int* counts   = (int*)(base + off);    off += (size_t)N * 4;
    int* offsets  = (int*)(base + off);    off += (size_t)N * 4;
    unsigned short* Wg1 = (unsigned short*)(base + off); off += 65536 * 2;
    unsigned short* Wg2 = (unsigned short*)(base + off); off += 65536 * 2;
    int* bucket_counts = (int*)(base + off); off += NB_MAX * 4;
    int* bucket_base   = (int*)(base + off); off += (NB_MAX + 1) * 4;
    off = (off + 15) & ~(size_t)15;
    int* bucket_cursor = (int*)(base + off); off += NB_MAX * 4;

    unsigned* pairs = (unsigned*)agg16;  // aliases agg16 (consumed before agg16 written)

    const int chunk = (E + PART_BLOCKS - 1) / PART_BLOCKS;

    // converts
    hipLaunchKernelGGL(convert_w_k, dim3(128), dim3(256), 0, stream, W1s, W1n, Wg1);
    hipLaunchKernelGGL(convert_w_k, dim3(128), dim3(256), 0, stream, W2s, W2n, Wg2);
    {
        int n4 = (N * D) / 4;
        hipLaunchKernelGGL(convert_x_k, dim3((n4 + 255) / 256), dim3(256), 0, stream,
                           in_feat, xh16, n4);
    }

    // CSR build (bucketed counting sort by dst)
    hipLaunchKernelGGL(zero_buckets_k, dim3((NB + 255) / 256), dim3(256), 0, stream,
                       bucket_counts, NB);
    hipLaunchKernelGGL(bucket_count_k, dim3(PART_BLOCKS), dim3(256), 0, stream,
                       dst, bucket_counts, E, NB);
    hipLaunchKernelGGL(bucket_scan_k, dim3(1), dim3(256), 0, stream,
                       bucket_counts, bucket_base, bucket_cursor, NB);
    hipLaunchKernelGGL(partition_k, dim3(PART_BLOCKS), dim3(256), 0, stream,
                       src, dst, bucket_cursor, pairs, E, NB, chunk);
    hipLaunchKernelGGL(build_csr_k, dim3(NB), dim3(256), 0, stream,
                       pairs, bucket_base, counts, offsets, edge_src, N);

    const dim3 aggGrid(((size_t)N * 64 + 255) / 256);
    const dim3 gemmGrid((N + 127) / 128);

    // layer 1: agg(x16) -> gemm -> h16 (in-place into xh16; fp32 h never materialized)
    hipLaunchKernelGGL(aggregate_f16_k, aggGrid, dim3(256), 0, stream,
                       xh16, edge_src, offsets, counts, agg16, N);
    hipLaunchKernelGGL(mfma_gemm_k, gemmGrid, dim3(256), 0, stream,
                       (const _Float16*)xh16, (const _Float16*)agg16, Wg1, b1,
                       (float*)nullptr, xh16, N, 1);

    // layer 2: agg(h16) -> gemm -> d_out fp32
    hipLaunchKernelGGL(aggregate_f16_k, aggGrid, dim3(256), 0, stream,
                       xh16, edge_src, offsets, counts, agg16, N);
    hipLaunchKernelGGL(mfma_gemm_k, gemmGrid, dim3(256), 0, stream,
                       (const _Float16*)xh16, (const _Float16*)agg16, Wg2, b2,
                       (float*)d_out, (__half*)nullptr, N, 0);
}

// Round 5
// 352.439 us; speedup vs baseline: 2.0724x; 1.1094x over previous
//
#include <hip/hip_runtime.h>
#include <hip/hip_fp16.h>

#define D 128
#define NB_MAX 1024
#define PART_BLOCKS 512

using f32x4  = __attribute__((ext_vector_type(4))) float;
using half8  = __attribute__((ext_vector_type(8))) _Float16;
using short8 = __attribute__((ext_vector_type(8))) short;

#define AS1(p) ((const __attribute__((address_space(1))) void*)(p))
#define AS3(p) ((__attribute__((address_space(3))) void*)(p))

// ------------------------------------------------ fused prep:
//  blocks [0,xb)            : x fp32 -> fp16
//  blocks [xb, xb+128)      : W1 -> f16 hi/lo planes (k-major swizzle)
//  blocks [xb+256, xb+384)  : W2 -> same
//  blocks [xb+512, ...)     : zero bucket_counts
// Wg layout: (((kc*2 + plane)*4 + q)*128 + col)*8 + j ; k = kc*32+q*8+j
__global__ void prep_k(const float* __restrict__ x, __half* __restrict__ y, int n4,
                       const float* __restrict__ W1s, const float* __restrict__ W1n,
                       const float* __restrict__ W2s, const float* __restrict__ W2n,
                       unsigned short* __restrict__ Wg1, unsigned short* __restrict__ Wg2,
                       int* __restrict__ bucket_counts, int nb, int xb) {
    int b = blockIdx.x;
    int t = threadIdx.x;
    if (b < xb) {
        int i = b * 256 + t;
        if (i < n4) {
            float4 v = *(const float4*)(x + (size_t)i * 4);
            __half2 h0 = __floats2half2_rn(v.x, v.y);
            __half2 h1 = __floats2half2_rn(v.z, v.w);
            __half2* o = (__half2*)(y + (size_t)i * 4);
            o[0] = h0; o[1] = h1;
        }
        return;
    }
    int wb = b - xb;
    if (wb < 512) {   // 128 blocks W1 (wb<128 as wb>>7==0), next 128: W2 at wb in [256,384)
        int sel = wb >> 8;              // 0: W1, 1: W2
        int lb  = wb & 255;
        if (lb >= 128) return;
        const float* Ws = sel ? W2s : W1s;
        const float* Wn = sel ? W2n : W1n;
        unsigned short* Wg = sel ? Wg2 : Wg1;
        int idx = lb * 256 + t;          // 0 .. 32767
        int col = idx >> 8;
        int k   = idx & 255;
        float v = (k < 128) ? Ws[k * D + col] : Wn[(k - 128) * D + col];
        _Float16 hv = (_Float16)v;
        _Float16 lv = (_Float16)(v - (float)hv);
        int kc = k >> 5, q = (k >> 3) & 3, j = k & 7;
        Wg[(((kc * 2 + 0) * 4 + q) * 128 + col) * 8 + j] = *(unsigned short*)&hv;
        Wg[(((kc * 2 + 1) * 4 + q) * 128 + col) * 8 + j] = *(unsigned short*)&lv;
        return;
    }
    int i = (wb - 512) * 256 + t;
    if (i < nb) bucket_counts[i] = 0;
}

// ------------------------------------------------ CSR build, bucketed (256 nodes/bucket)
__global__ void bucket_count_k(const int* __restrict__ dst, int* __restrict__ bucket_counts,
                               int E, int nb) {
    __shared__ int hist[NB_MAX];
    int t = threadIdx.x;
    for (int b = t; b < nb; b += 256) hist[b] = 0;
    __syncthreads();
    for (int i = blockIdx.x * 256 + t; i < E; i += gridDim.x * 256)
        atomicAdd(&hist[dst[i] >> 8], 1);
    __syncthreads();
    for (int b = t; b < nb; b += 256) {
        int c = hist[b];
        if (c) atomicAdd(&bucket_counts[b], c);
    }
}

__global__ void bucket_scan_k(const int* __restrict__ bucket_counts,
                              int* __restrict__ bucket_base,
                              int* __restrict__ bucket_cursor, int nb) {
    __shared__ int sh[256];
    int t = threadIdx.x;
    int base = t * 4;
    int v0 = (base + 0 < nb) ? bucket_counts[base + 0] : 0;
    int v1 = (base + 1 < nb) ? bucket_counts[base + 1] : 0;
    int v2 = (base + 2 < nb) ? bucket_counts[base + 2] : 0;
    int v3 = (base + 3 < nb) ? bucket_counts[base + 3] : 0;
    int tsum = v0 + v1 + v2 + v3;
    sh[t] = tsum;
    __syncthreads();
    for (int off = 1; off < 256; off <<= 1) {
        int x = 0;
        if (t >= off) x = sh[t - off];
        __syncthreads();
        if (t >= off) sh[t] += x;
        __syncthreads();
    }
    int excl = sh[t] - tsum;
    if (base + 0 < nb) { bucket_base[base+0] = excl;          bucket_cursor[base+0] = excl; }
    if (base + 1 < nb) { bucket_base[base+1] = excl+v0;       bucket_cursor[base+1] = excl+v0; }
    if (base + 2 < nb) { bucket_base[base+2] = excl+v0+v1;    bucket_cursor[base+2] = excl+v0+v1; }
    if (base + 3 < nb) { bucket_base[base+3] = excl+v0+v1+v2; bucket_cursor[base+3] = excl+v0+v1+v2; }
    if (t == 255) bucket_base[nb] = sh[255];
}

__global__ void partition_k(const int* __restrict__ src, const int* __restrict__ dst,
                            int* __restrict__ bucket_cursor, unsigned* __restrict__ pairs,
                            int E, int nb, int chunk) {
    __shared__ int hist[NB_MAX];
    __shared__ int bbase[NB_MAX];
    int t = threadIdx.x;
    int e0 = blockIdx.x * chunk;
    int e1 = min(E, e0 + chunk);
    for (int b = t; b < nb; b += 256) hist[b] = 0;
    __syncthreads();
    for (int i = e0 + t; i < e1; i += 256)
        atomicAdd(&hist[dst[i] >> 8], 1);
    __syncthreads();
    for (int b = t; b < nb; b += 256) {
        int c = hist[b];
        int bs = 0;
        if (c) bs = atomicAdd(&bucket_cursor[b], c);
        bbase[b] = bs;
        hist[b] = 0;            // reuse as local cursor
    }
    __syncthreads();
    for (int i = e0 + t; i < e1; i += 256) {
        int dd = dst[i];
        int b = dd >> 8;
        int r = atomicAdd(&hist[b], 1);
        pairs[bbase[b] + r] = ((unsigned)(dd & 255) << 17) | (unsigned)src[i];
    }
}

__global__ void build_csr_k(const unsigned* __restrict__ pairs,
                            const int* __restrict__ bucket_base,
                            int* __restrict__ counts, int* __restrict__ offsets,
                            int* __restrict__ edge_src, int N) {
    __shared__ int hist[256];
    __shared__ int curs[256];
    __shared__ int sh[256];
    int t = threadIdx.x;
    int b = blockIdx.x;
    int n0 = b << 8;
    int e0 = bucket_base[b];
    int e1 = bucket_base[b + 1];
    hist[t] = 0;
    __syncthreads();
    for (int i = e0 + t; i < e1; i += 256)
        atomicAdd(&hist[pairs[i] >> 17], 1);
    __syncthreads();
    int c = hist[t];
    sh[t] = c;
    __syncthreads();
    for (int off = 1; off < 256; off <<= 1) {
        int x = 0;
        if (t >= off) x = sh[t - off];
        __syncthreads();
        if (t >= off) sh[t] += x;
        __syncthreads();
    }
    int excl = sh[t] - c;
    curs[t] = excl;
    int node = n0 + t;
    if (node < N) { counts[node] = c; offsets[node] = e0 + excl; }
    __syncthreads();
    for (int i = e0 + t; i < e1; i += 256) {
        unsigned p = pairs[i];
        int pos = atomicAdd(&curs[p >> 17], 1);
        edge_src[e0 + pos] = (int)(p & 0x1FFFFu);
    }
}

// ------------------------------------------------ neighbor mean, fp16 in/out
// one wave per dst node; 16 lanes x 16B per row; 16 edges per inner iter
// (4 batched loads per lane -> 4x memory-level parallelism).
__global__ void aggregate_f16_k(const __half* __restrict__ x,
                                const int* __restrict__ edge_src,
                                const int* __restrict__ offsets,
                                const int* __restrict__ counts,
                                __half* __restrict__ agg, int n) {
    int wid  = (blockIdx.x * blockDim.x + threadIdx.x) >> 6;
    int lane = threadIdx.x & 63;
    if (wid >= n) return;
    int sg  = lane >> 4;     // 0..3: edge slot within each group of 4
    int sub = lane & 15;     // 16 lanes cover one 256B row
    int start = offsets[wid];
    int cnt   = counts[wid];
    float acc[8] = {0.f, 0.f, 0.f, 0.f, 0.f, 0.f, 0.f, 0.f};
    for (int base = 0; base < cnt; base += 64) {
        int valid = min(64, cnt - base);
        int s = (lane < valid) ? edge_src[start + base + lane] : 0;
        for (int k0 = 0; k0 < valid; k0 += 16) {
            float4 raw[4];
            float  wg[4];
            #pragma unroll
            for (int u = 0; u < 4; ++u) {
                int idx = k0 + 4 * u + sg;
                int row = __shfl(s, idx & 63);
                wg[u] = (idx < valid) ? 1.0f : 0.0f;
                raw[u] = *(const float4*)(x + (size_t)row * D + sub * 8);
            }
            #pragma unroll
            for (int u = 0; u < 4; ++u) {
                const __half2* hp = (const __half2*)&raw[u];
                #pragma unroll
                for (int j = 0; j < 4; ++j) {
                    float2 f = __half22float2(hp[j]);
                    acc[2 * j]     = fmaf(f.x, wg[u], acc[2 * j]);
                    acc[2 * j + 1] = fmaf(f.y, wg[u], acc[2 * j + 1]);
                }
            }
        }
    }
    #pragma unroll
    for (int j = 0; j < 8; ++j) {
        acc[j] += __shfl(acc[j], lane ^ 16);
        acc[j] += __shfl(acc[j], lane ^ 32);
    }
    if (sg == 0) {
        float inv = 1.0f / fmaxf((float)cnt, 1.0f);
        union { __half2 h2[4]; short8 s8; } u;
        #pragma unroll
        for (int j = 0; j < 4; ++j)
            u.h2[j] = __floats2half2_rn(acc[2 * j] * inv, acc[2 * j + 1] * inv);
        *(short8*)(agg + (size_t)wid * D + sub * 8) = u.s8;
    }
}

// ------------------------------------------------ fp16 2-term MFMA GEMM, LDS-staged B
// C = A0 @ W[:128] + A1 @ W[128:] + b  with W = Whi + Wlo (f16 split)
// block = 512 thr = 8 waves = 256 rows sharing each 16KB B-stage (halves
// B L2 refetch + barriers per row vs 128-row blocks).
__global__ __launch_bounds__(512)
void mfma_gemm_k(const _Float16* __restrict__ A0, const _Float16* __restrict__ A1,
                 const unsigned short* __restrict__ Wg,
                 const float* __restrict__ bias,
                 float* __restrict__ C, __half* __restrict__ Ch,
                 int n, int out_mode) {
    __shared__ __align__(16) unsigned short lds_b[8192];   // 16 KB
    int t = threadIdx.x;
    int w = t >> 6;
    int l = t & 63;
    int m = l & 15;          // A row within tile / B,C col within tile
    int q = l >> 4;          // quad
    int r0 = blockIdx.x * 256 + w * 32;

    f32x4 acc[2][8];
    #pragma unroll
    for (int rt = 0; rt < 2; ++rt)
        #pragma unroll
        for (int ct = 0; ct < 8; ++ct)
            acc[rt][ct] = (f32x4){0.f, 0.f, 0.f, 0.f};

    for (int kc = 0; kc < 8; ++kc) {
        // async stage B chunk (16 KB contiguous) into LDS: 1024 x 16B, 2/thread
        const unsigned short* gk = Wg + (size_t)kc * 8192;
        #pragma unroll
        for (int i = 0; i < 2; ++i) {
            int e = i * 512 + t;
            __builtin_amdgcn_global_load_lds(AS1(gk + e * 8), AS3(lds_b + e * 8), 16, 0, 0);
        }
        // A fragments (fp16, 16B each) straight from global
        const _Float16* __restrict__ A = (kc < 4) ? A0 : A1;
        int ka = (kc & 3) * 32;
        half8 a[2];
        #pragma unroll
        for (int rt = 0; rt < 2; ++rt) {
            int row = r0 + rt * 16 + m;
            half8 v = (half8){0, 0, 0, 0, 0, 0, 0, 0};
            if (row < n) v = *(const half8*)(A + (size_t)row * D + ka + q * 8);
            a[rt] = v;
        }
        __syncthreads();     // drains global_load_lds + barrier

        #pragma unroll
        for (int ct = 0; ct < 8; ++ct) {
            half8 bh = *(const half8*)&lds_b[(size_t)(q * 128 + ct * 16 + m) * 8];
            half8 bl = *(const half8*)&lds_b[(size_t)((4 + q) * 128 + ct * 16 + m) * 8];
            #pragma unroll
            for (int rt = 0; rt < 2; ++rt) {
                acc[rt][ct] = __builtin_amdgcn_mfma_f32_16x16x32_f16(a[rt], bh, acc[rt][ct], 0, 0, 0);
                acc[rt][ct] = __builtin_amdgcn_mfma_f32_16x16x32_f16(a[rt], bl, acc[rt][ct], 0, 0, 0);
            }
        }
        __syncthreads();     // LDS reads done before next stage overwrites
    }

    #pragma unroll
    for (int ct = 0; ct < 8; ++ct) {
        int col = ct * 16 + m;
        float bb = bias[col];
        #pragma unroll
        for (int rt = 0; rt < 2; ++rt) {
            #pragma unroll
            for (int r = 0; r < 4; ++r) {
                int row = r0 + rt * 16 + q * 4 + r;
                if (row < n) {
                    float v = acc[rt][ct][r] + bb;
                    if (out_mode) {
                        v = fmaxf(v, 0.f);
                        Ch[(size_t)row * D + col] = __float2half(v);
                    } else {
                        C[(size_t)row * D + col] = v;
                    }
                }
            }
        }
    }
}

// ------------------------------------------------------------------- launch
extern "C" void kernel_launch(void* const* d_in, const int* in_sizes, int n_in,
                              void* d_out, int out_size, void* d_ws, size_t ws_size,
                              hipStream_t stream) {
    const float* in_feat = (const float*)d_in[0];
    const float* W1s     = (const float*)d_in[1];
    const float* W1n     = (const float*)d_in[2];
    const float* b1      = (const float*)d_in[3];
    const float* W2s     = (const float*)d_in[4];
    const float* W2n     = (const float*)d_in[5];
    const float* b2      = (const float*)d_in[6];
    const int*   src     = (const int*)d_in[7];
    const int*   dst     = (const int*)d_in[8];

    const int N  = in_sizes[0] / D;
    const int E  = in_sizes[7];
    const int NB = (N + 255) >> 8;     // 256-node buckets

    // workspace layout
    char* base = (char*)d_ws;
    size_t off = 0;
    __half* agg16 = (__half*)(base + off); off += (size_t)N * D * 2;   // neighbor means
    __half* xh16  = (__half*)(base + off); off += (size_t)N * D * 2;   // x16, then h16 (in-place)
    int* edge_src = (int*)(base + off);    off += (size_t)E * 4;
    int* counts   = (int*)(base + off);    off += (size_t)N * 4;
    int* offsets  = (int*)(base + off);    off += (size_t)N * 4;
    unsigned short* Wg1 = (unsigned short*)(base + off); off += 65536 * 2;
    unsigned short* Wg2 = (unsigned short*)(base + off); off += 65536 * 2;
    int* bucket_counts = (int*)(base + off); off += NB_MAX * 4;
    int* bucket_base   = (int*)(base + off); off += (NB_MAX + 1) * 4;
    off = (off + 15) & ~(size_t)15;
    int* bucket_cursor = (int*)(base + off); off += NB_MAX * 4;

    unsigned* pairs = (unsigned*)agg16;  // aliases agg16 (consumed before agg16 written)

    const int chunk = (E + PART_BLOCKS - 1) / PART_BLOCKS;
    const int n4 = (N * D) / 4;
    const int xb = (n4 + 255) / 256;
    const int zb = (NB + 255) / 256;

    // fused prep: x->fp16, W1/W2 hi-lo split, zero bucket counts
    hipLaunchKernelGGL(prep_k, dim3(xb + 512 + zb), dim3(256), 0, stream,
                       in_feat, xh16, n4, W1s, W1n, W2s, W2n, Wg1, Wg2,
                       bucket_counts, NB, xb);

    // CSR build (bucketed counting sort by dst)
    hipLaunchKernelGGL(bucket_count_k, dim3(PART_BLOCKS), dim3(256), 0, stream,
                       dst, bucket_counts, E, NB);
    hipLaunchKernelGGL(bucket_scan_k, dim3(1), dim3(256), 0, stream,
                       bucket_counts, bucket_base, bucket_cursor, NB);
    hipLaunchKernelGGL(partition_k, dim3(PART_BLOCKS), dim3(256), 0, stream,
                       src, dst, bucket_cursor, pairs, E, NB, chunk);
    hipLaunchKernelGGL(build_csr_k, dim3(NB), dim3(256), 0, stream,
                       pairs, bucket_base, counts, offsets, edge_src, N);

    const dim3 aggGrid(((size_t)N * 64 + 255) / 256);
    const dim3 gemmGrid((N + 255) / 256);

    // layer 1: agg(x16) -> gemm -> h16 (in-place into xh16; fp32 h never materialized)
    hipLaunchKernelGGL(aggregate_f16_k, aggGrid, dim3(256), 0, stream,
                       xh16, edge_src, offsets, counts, agg16, N);
    hipLaunchKernelGGL(mfma_gemm_k, gemmGrid, dim3(512), 0, stream,
                       (const _Float16*)xh16, (const _Float16*)agg16, Wg1, b1,
                       (float*)nullptr, xh16, N, 1);

    // layer 2: agg(h16) -> gemm -> d_out fp32
    hipLaunchKernelGGL(aggregate_f16_k, aggGrid, dim3(256), 0, stream,
                       xh16, edge_src, offsets, counts, agg16, N);
    hipLaunchKernelGGL(mfma_gemm_k, gemmGrid, dim3(512), 0, stream,
                       (const _Float16*)xh16, (const _Float16*)agg16, Wg2, b2,
                       (float*)d_out, (__half*)nullptr, N, 0);
}